// Round 1
// baseline (2097.311 us; speedup 1.0000x reference)
//
#include <hip/hip_runtime.h>
#include <hip/hip_bf16.h>

#define NNODES 500000

// ---------------- degree count ----------------
__global__ void deg_kernel(const int* __restrict__ dst, float* __restrict__ deg, int E) {
    int e = blockIdx.x * blockDim.x + threadIdx.x;
    if (e < E) unsafeAtomicAdd(&deg[dst[e]], 1.0f);
}

// in-place: dinv = rsqrt(deg + 1)  (+1 = self loop; always > 0)
__global__ void dinv_kernel(float* __restrict__ deg_dinv, int n) {
    int i = blockIdx.x * blockDim.x + threadIdx.x;
    if (i < n) deg_dinv[i] = rsqrtf(deg_dinv[i] + 1.0f);
}

// ---------------- layer 1 aggregation (width 3) ----------------
__global__ void scatter1_kernel(const int* __restrict__ src, const int* __restrict__ dst,
                                const float* __restrict__ dinv, const float* __restrict__ x,
                                float* __restrict__ agg1, int E) {
    int e = blockIdx.x * blockDim.x + threadIdx.x;
    if (e >= E) return;
    int s = src[e], d = dst[e];
    float nrm = dinv[s] * dinv[d];
    const float* xs = x + 3 * s;
    float* a = agg1 + 3 * d;
    unsafeAtomicAdd(a + 0, nrm * xs[0]);
    unsafeAtomicAdd(a + 1, nrm * xs[1]);
    unsafeAtomicAdd(a + 2, nrm * xs[2]);
}

// per-node: add self-loop, 3x16 matmul + bias, relu -> h1
__global__ void transform1_kernel(const float* __restrict__ x, const float* __restrict__ agg1,
                                  const float* __restrict__ dinv,
                                  const float* __restrict__ W1, const float* __restrict__ b1,
                                  float* __restrict__ h1, int n) {
    int v = blockIdx.x * blockDim.x + threadIdx.x;
    if (v >= n) return;
    float di = dinv[v];
    float sl = di * di;
    float a0 = agg1[3 * v + 0] + sl * x[3 * v + 0];
    float a1 = agg1[3 * v + 1] + sl * x[3 * v + 1];
    float a2 = agg1[3 * v + 2] + sl * x[3 * v + 2];
    float* hv = h1 + 16 * v;
#pragma unroll
    for (int j = 0; j < 16; ++j) {
        float h = b1[j] + a0 * W1[0 * 16 + j] + a1 * W1[1 * 16 + j] + a2 * W1[2 * 16 + j];
        hv[j] = fmaxf(h, 0.0f);
    }
}

// ---------------- layer 2 aggregation (width 16, feature-parallel) ----------------
__global__ void scatter2_kernel(const int* __restrict__ src, const int* __restrict__ dst,
                                const float* __restrict__ dinv, const float* __restrict__ h1,
                                float* __restrict__ agg2, int E) {
    int idx = blockIdx.x * blockDim.x + threadIdx.x;   // 16*E total, fits int (128M)
    if (idx >= 16 * E) return;
    int e = idx >> 4;
    int f = idx & 15;
    int s = src[e], d = dst[e];
    float nrm = dinv[s] * dinv[d];
    unsafeAtomicAdd(&agg2[16 * d + f], nrm * h1[16 * s + f]);
}

// per-node: self-loop, 16x10 matmul + bias, log_softmax -> out
__global__ void transform2_kernel(const float* __restrict__ h1, const float* __restrict__ agg2,
                                  const float* __restrict__ dinv,
                                  const float* __restrict__ W2, const float* __restrict__ b2,
                                  float* __restrict__ out, int n) {
    int v = blockIdx.x * blockDim.x + threadIdx.x;
    if (v >= n) return;
    float di = dinv[v];
    float sl = di * di;
    float a[16];
#pragma unroll
    for (int k = 0; k < 16; ++k) a[k] = agg2[16 * v + k] + sl * h1[16 * v + k];
    float z[10];
#pragma unroll
    for (int j = 0; j < 10; ++j) {
        float acc = b2[j];
#pragma unroll
        for (int k = 0; k < 16; ++k) acc += a[k] * W2[k * 10 + j];
        z[j] = acc;
    }
    float m = z[0];
#pragma unroll
    for (int j = 1; j < 10; ++j) m = fmaxf(m, z[j]);
    float sum = 0.0f;
#pragma unroll
    for (int j = 0; j < 10; ++j) sum += expf(z[j] - m);
    float lse = logf(sum);
    float* ov = out + 10 * v;
#pragma unroll
    for (int j = 0; j < 10; ++j) ov[j] = z[j] - m - lse;
}

extern "C" void kernel_launch(void* const* d_in, const int* in_sizes, int n_in,
                              void* d_out, int out_size, void* d_ws, size_t ws_size,
                              hipStream_t stream) {
    const float* x  = (const float*)d_in[0];
    const int*   ei = (const int*)d_in[1];
    const float* W1 = (const float*)d_in[2];
    const float* b1 = (const float*)d_in[3];
    const float* W2 = (const float*)d_in[4];
    const float* b2 = (const float*)d_in[5];
    float* out = (float*)d_out;

    const int N = NNODES;
    const int E = in_sizes[1] / 2;           // 8,000,000
    const int* src = ei;
    const int* dst = ei + E;

    float* ws   = (float*)d_ws;
    float* dinv = ws;                         // N   (deg -> dinv in place)
    float* agg1 = ws + (size_t)N;             // 3N
    float* h1   = ws + (size_t)4 * N;         // 16N
    float* agg2 = ws + (size_t)20 * N;        // 16N   total 36N floats = 72 MB

    // zero deg+agg1 (contiguous first 4N) and agg2
    hipMemsetAsync(ws, 0, (size_t)4 * N * sizeof(float), stream);
    hipMemsetAsync(agg2, 0, (size_t)16 * N * sizeof(float), stream);

    const int B = 256;
    deg_kernel<<<(E + B - 1) / B, B, 0, stream>>>(dst, dinv, E);
    dinv_kernel<<<(N + B - 1) / B, B, 0, stream>>>(dinv, N);
    scatter1_kernel<<<(E + B - 1) / B, B, 0, stream>>>(src, dst, dinv, x, agg1, E);
    transform1_kernel<<<(N + B - 1) / B, B, 0, stream>>>(x, agg1, dinv, W1, b1, h1, N);
    int total2 = 16 * E;
    scatter2_kernel<<<(total2 + B - 1) / B, B, 0, stream>>>(src, dst, dinv, h1, agg2, E);
    transform2_kernel<<<(N + B - 1) / B, B, 0, stream>>>(h1, agg2, dinv, W2, b2, out, N);
}

// Round 2
// 1310.813 us; speedup vs baseline: 1.6000x; 1.6000x over previous
//
#include <hip/hip_runtime.h>
#include <hip/hip_bf16.h>

#define NNODES 500000

// ---------------- degree count ----------------
__global__ void deg_kernel(const int* __restrict__ dst, float* __restrict__ deg, int E) {
    int e = blockIdx.x * blockDim.x + threadIdx.x;
    if (e < E) unsafeAtomicAdd(&deg[dst[e]], 1.0f);
}

// dinv = rsqrt(deg+1) (in place); y1[4v+f] = dinv * x[3v+f], pad f=3 with 0
__global__ void dinv_y1_kernel(float* __restrict__ deg_dinv, const float* __restrict__ x,
                               float* __restrict__ y1, int n) {
    int v = blockIdx.x * blockDim.x + threadIdx.x;
    if (v >= n) return;
    float di = rsqrtf(deg_dinv[v] + 1.0f);
    deg_dinv[v] = di;
    float* yv = y1 + 4 * v;
    yv[0] = di * x[3 * v + 0];
    yv[1] = di * x[3 * v + 1];
    yv[2] = di * x[3 * v + 2];
    yv[3] = 0.0f;
}

// ---------------- layer 1 aggregation: 4 lanes per edge, fully coalesced ----------------
__global__ void scatter1_kernel(const int* __restrict__ src, const int* __restrict__ dst,
                                const float* __restrict__ y1, float* __restrict__ agg1, int E) {
    int idx = blockIdx.x * blockDim.x + threadIdx.x;   // 4*E = 32M
    if (idx >= 4 * E) return;
    int e = idx >> 2;
    int f = idx & 3;
    int s = src[e], d = dst[e];
    unsafeAtomicAdd(&agg1[4 * d + f], y1[4 * s + f]);  // f=3 adds 0 into pad (same 16B txn)
}

// per-node: a = dinv*(agg1 + dinv*x); h = relu(W1^T a + b1); y2 = dinv*h
__global__ void transform1_kernel(const float* __restrict__ x, const float* __restrict__ agg1,
                                  const float* __restrict__ dinv,
                                  const float* __restrict__ W1, const float* __restrict__ b1,
                                  float* __restrict__ y2, int n) {
    int v = blockIdx.x * blockDim.x + threadIdx.x;
    if (v >= n) return;
    float di = dinv[v];
    float a0 = di * (agg1[4 * v + 0] + di * x[3 * v + 0]);
    float a1 = di * (agg1[4 * v + 1] + di * x[3 * v + 1]);
    float a2 = di * (agg1[4 * v + 2] + di * x[3 * v + 2]);
    float* yv = y2 + 16 * v;
#pragma unroll
    for (int j = 0; j < 16; ++j) {
        float h = b1[j] + a0 * W1[0 * 16 + j] + a1 * W1[1 * 16 + j] + a2 * W1[2 * 16 + j];
        yv[j] = di * fmaxf(h, 0.0f);
    }
}

// ---------------- layer 2 aggregation: 16 lanes per edge ----------------
__global__ void scatter2_kernel(const int* __restrict__ src, const int* __restrict__ dst,
                                const float* __restrict__ y2, float* __restrict__ agg2, int E) {
    int idx = blockIdx.x * blockDim.x + threadIdx.x;   // 16*E = 128M
    if (idx >= 16 * E) return;
    int e = idx >> 4;
    int f = idx & 15;
    int s = src[e], d = dst[e];
    unsafeAtomicAdd(&agg2[16 * d + f], y2[16 * s + f]);
}

// per-node: a = dinv*(agg2 + y2); z = W2^T a + b2; out = log_softmax(z)
__global__ void transform2_kernel(const float* __restrict__ y2, const float* __restrict__ agg2,
                                  const float* __restrict__ dinv,
                                  const float* __restrict__ W2, const float* __restrict__ b2,
                                  float* __restrict__ out, int n) {
    int v = blockIdx.x * blockDim.x + threadIdx.x;
    if (v >= n) return;
    float di = dinv[v];
    float a[16];
#pragma unroll
    for (int k = 0; k < 16; ++k) a[k] = di * (agg2[16 * v + k] + y2[16 * v + k]);
    float z[10];
#pragma unroll
    for (int j = 0; j < 10; ++j) {
        float acc = b2[j];
#pragma unroll
        for (int k = 0; k < 16; ++k) acc += a[k] * W2[k * 10 + j];
        z[j] = acc;
    }
    float m = z[0];
#pragma unroll
    for (int j = 1; j < 10; ++j) m = fmaxf(m, z[j]);
    float sum = 0.0f;
#pragma unroll
    for (int j = 0; j < 10; ++j) sum += expf(z[j] - m);
    float lse = logf(sum);
    float* ov = out + 10 * v;
#pragma unroll
    for (int j = 0; j < 10; ++j) ov[j] = z[j] - m - lse;
}

extern "C" void kernel_launch(void* const* d_in, const int* in_sizes, int n_in,
                              void* d_out, int out_size, void* d_ws, size_t ws_size,
                              hipStream_t stream) {
    const float* x  = (const float*)d_in[0];
    const int*   ei = (const int*)d_in[1];
    const float* W1 = (const float*)d_in[2];
    const float* b1 = (const float*)d_in[3];
    const float* W2 = (const float*)d_in[4];
    const float* b2 = (const float*)d_in[5];
    float* out = (float*)d_out;

    const int N = NNODES;
    const int E = in_sizes[1] / 2;            // 8,000,000
    const int* src = ei;
    const int* dst = ei + E;

    float* ws   = (float*)d_ws;
    float* dinv = ws;                          // N    (deg -> dinv in place)
    float* y1   = ws + (size_t)N;              // 4N   (padded, dinv*x)
    float* agg1 = ws + (size_t)5 * N;          // 4N   (padded)
    float* y2   = ws + (size_t)9 * N;          // 16N  (dinv*relu(h1))
    float* agg2 = ws + (size_t)25 * N;         // 16N  -> total 41N floats = 82 MB

    hipMemsetAsync(dinv, 0, (size_t)N * sizeof(float), stream);
    hipMemsetAsync(agg1, 0, (size_t)4 * N * sizeof(float), stream);
    hipMemsetAsync(agg2, 0, (size_t)16 * N * sizeof(float), stream);

    const int B = 256;
    deg_kernel<<<(E + B - 1) / B, B, 0, stream>>>(dst, dinv, E);
    dinv_y1_kernel<<<(N + B - 1) / B, B, 0, stream>>>(dinv, x, y1, N);
    int total1 = 4 * E;
    scatter1_kernel<<<(total1 + B - 1) / B, B, 0, stream>>>(src, dst, y1, agg1, E);
    transform1_kernel<<<(N + B - 1) / B, B, 0, stream>>>(x, agg1, dinv, W1, b1, y2, N);
    int total2 = 16 * E;
    scatter2_kernel<<<(total2 + B - 1) / B, B, 0, stream>>>(src, dst, y2, agg2, E);
    transform2_kernel<<<(N + B - 1) / B, B, 0, stream>>>(y2, agg2, dinv, W2, b2, out, N);
}

// Round 3
// 1193.282 us; speedup vs baseline: 1.7576x; 1.0985x over previous
//
#include <hip/hip_runtime.h>
#include <hip/hip_bf16.h>

#define NNODES 500000
#define BSHIFT 9
#define BSIZE  512          // nodes per bucket
#define NB_PAD 1024         // padded bucket count (NB = 977 for N=500000)
#define GPLACE 512          // blocks for histogram / placement

// ---------- pass 1: global histogram of dst buckets ----------
__global__ __launch_bounds__(256) void hist_kernel(const int* __restrict__ dst,
                                                   int* __restrict__ bucket_count, int E) {
    __shared__ unsigned int h[NB_PAD];
    for (int i = threadIdx.x; i < NB_PAD; i += blockDim.x) h[i] = 0u;
    __syncthreads();
    int stride = gridDim.x * blockDim.x;
    for (int i = blockIdx.x * blockDim.x + threadIdx.x; i < E; i += stride)
        atomicAdd(&h[((unsigned)dst[i]) >> BSHIFT], 1u);
    __syncthreads();
    for (int b = threadIdx.x; b < NB_PAD; b += blockDim.x) {
        unsigned c = h[b];
        if (c) atomicAdd(&bucket_count[b], (int)c);
    }
}

// ---------- pass 2: exclusive scan over 1024 buckets (single block) ----------
__global__ __launch_bounds__(NB_PAD) void scan_kernel(const int* __restrict__ bucket_count,
                                                      int* __restrict__ base,
                                                      int* __restrict__ cursor) {
    __shared__ int s[NB_PAD];
    int t = threadIdx.x;
    int v = bucket_count[t];
    s[t] = v;
    __syncthreads();
    for (int off = 1; off < NB_PAD; off <<= 1) {
        int val = (t >= off) ? s[t - off] : 0;
        __syncthreads();
        s[t] += val;
        __syncthreads();
    }
    int excl = s[t] - v;
    base[t] = excl;
    cursor[t] = excl;
    if (t == NB_PAD - 1) base[NB_PAD] = s[t];
}

// ---------- pass 3: place edges into dst-bucket-sorted packed array ----------
// packed edge word: (dst & 511) << 19 | src   (src < 2^19, 500000 < 524288)
__global__ __launch_bounds__(256) void place_kernel(const int* __restrict__ src,
                                                    const int* __restrict__ dst,
                                                    int* __restrict__ cursor,
                                                    unsigned int* __restrict__ packed,
                                                    int E, int C) {
    __shared__ unsigned int h[NB_PAD];
    __shared__ int cur[NB_PAD];
    for (int i = threadIdx.x; i < NB_PAD; i += blockDim.x) h[i] = 0u;
    __syncthreads();
    int lo = blockIdx.x * C;
    int hi = min(E, lo + C);
    for (int i = lo + threadIdx.x; i < hi; i += blockDim.x)
        atomicAdd(&h[((unsigned)dst[i]) >> BSHIFT], 1u);
    __syncthreads();
    for (int b = threadIdx.x; b < NB_PAD; b += blockDim.x) {
        unsigned c = h[b];
        cur[b] = c ? atomicAdd(&cursor[b], (int)c) : 0;
    }
    __syncthreads();
    for (int i = lo + threadIdx.x; i < hi; i += blockDim.x) {
        unsigned d = (unsigned)dst[i];
        unsigned b = d >> BSHIFT;
        int pos = atomicAdd(&cur[b], 1);
        packed[pos] = ((d & (unsigned)(BSIZE - 1)) << 19) | (unsigned)src[i];
    }
}

// ---------- pass 4: per-node degree (LDS count) -> dinv ----------
__global__ __launch_bounds__(256) void degdinv_kernel(const unsigned int* __restrict__ packed,
                                                      const int* __restrict__ base,
                                                      float* __restrict__ dinv, int n) {
    __shared__ unsigned int cnt[BSIZE];
    int b = blockIdx.x;
    for (int i = threadIdx.x; i < BSIZE; i += blockDim.x) cnt[i] = 0u;
    __syncthreads();
    int beg = base[b], end = base[b + 1];
    for (int i = beg + threadIdx.x; i < end; i += blockDim.x)
        atomicAdd(&cnt[packed[i] >> 19], 1u);
    __syncthreads();
    int v0 = b << BSHIFT;
    for (int l = threadIdx.x; l < BSIZE; l += blockDim.x) {
        int v = v0 + l;
        if (v < n) dinv[v] = rsqrtf((float)cnt[l] + 1.0f);
    }
}

// ---------- y1 = dinv * x, padded to stride 4 ----------
__global__ __launch_bounds__(256) void y1_kernel(const float* __restrict__ dinv,
                                                 const float* __restrict__ x,
                                                 float* __restrict__ y1, int n) {
    int v = blockIdx.x * blockDim.x + threadIdx.x;
    if (v >= n) return;
    float di = dinv[v];
    float* yv = y1 + 4 * v;
    yv[0] = di * x[3 * v + 0];
    yv[1] = di * x[3 * v + 1];
    yv[2] = di * x[3 * v + 2];
    yv[3] = 0.0f;
}

// ---------- layer 1: LDS aggregate + fused transform -> y2 = dinv*relu(W1^T a + b1) ----------
__global__ __launch_bounds__(256) void agg1t1_kernel(const unsigned int* __restrict__ packed,
                                                     const int* __restrict__ base,
                                                     const float* __restrict__ y1,
                                                     const float* __restrict__ dinv,
                                                     const float* __restrict__ W1,
                                                     const float* __restrict__ b1,
                                                     float* __restrict__ y2, int n) {
    __shared__ float acc[BSIZE * 4];          // 8 KB
    int b = blockIdx.x;
    for (int i = threadIdx.x; i < BSIZE * 4; i += blockDim.x) acc[i] = 0.0f;
    __syncthreads();
    int beg = base[b], end = base[b + 1];
    int f = threadIdx.x & 3;
    for (int i = beg + (threadIdx.x >> 2); i < end; i += (blockDim.x >> 2)) {
        unsigned p = packed[i];
        unsigned s = p & 0x7FFFFu;
        unsigned dl = p >> 19;
        atomicAdd(&acc[dl * 4 + f], y1[4 * s + f]);
    }
    __syncthreads();
    int v0 = b << BSHIFT;
    for (int l = threadIdx.x; l < BSIZE; l += blockDim.x) {
        int v = v0 + l;
        if (v >= n) continue;
        float di = dinv[v];
        float a0 = di * (acc[l * 4 + 0] + y1[4 * v + 0]);
        float a1 = di * (acc[l * 4 + 1] + y1[4 * v + 1]);
        float a2 = di * (acc[l * 4 + 2] + y1[4 * v + 2]);
        float* yv = y2 + 16 * v;
#pragma unroll
        for (int j = 0; j < 16; ++j) {
            float h = b1[j] + a0 * W1[0 * 16 + j] + a1 * W1[1 * 16 + j] + a2 * W1[2 * 16 + j];
            yv[j] = di * fmaxf(h, 0.0f);
        }
    }
}

// ---------- layer 2: LDS aggregate + fused transform + log_softmax -> out ----------
__global__ __launch_bounds__(256) void agg2t2_kernel(const unsigned int* __restrict__ packed,
                                                     const int* __restrict__ base,
                                                     const float* __restrict__ y2,
                                                     const float* __restrict__ dinv,
                                                     const float* __restrict__ W2,
                                                     const float* __restrict__ b2,
                                                     float* __restrict__ out, int n) {
    __shared__ float acc[BSIZE * 16];         // 32 KB
    int b = blockIdx.x;
    for (int i = threadIdx.x; i < BSIZE * 16; i += blockDim.x) acc[i] = 0.0f;
    __syncthreads();
    int beg = base[b], end = base[b + 1];
    int f = threadIdx.x & 15;
    for (int i = beg + (threadIdx.x >> 4); i < end; i += (blockDim.x >> 4)) {
        unsigned p = packed[i];
        unsigned s = p & 0x7FFFFu;
        unsigned dl = p >> 19;
        atomicAdd(&acc[dl * 16 + f], y2[16 * s + f]);
    }
    __syncthreads();
    int v0 = b << BSHIFT;
    for (int l = threadIdx.x; l < BSIZE; l += blockDim.x) {
        int v = v0 + l;
        if (v >= n) continue;
        float di = dinv[v];
        float a[16];
#pragma unroll
        for (int k = 0; k < 16; ++k) {
            int kk = (k + l) & 15;            // stagger LDS banks across lanes
            a[kk] = di * (acc[l * 16 + kk] + y2[16 * v + kk]);
        }
        float z[10];
#pragma unroll
        for (int j = 0; j < 10; ++j) {
            float acc2 = b2[j];
#pragma unroll
            for (int k = 0; k < 16; ++k) acc2 += a[k] * W2[k * 10 + j];
            z[j] = acc2;
        }
        float m = z[0];
#pragma unroll
        for (int j = 1; j < 10; ++j) m = fmaxf(m, z[j]);
        float sum = 0.0f;
#pragma unroll
        for (int j = 0; j < 10; ++j) sum += expf(z[j] - m);
        float lse = logf(sum);
        float* ov = out + 10 * v;
#pragma unroll
        for (int j = 0; j < 10; ++j) ov[j] = z[j] - m - lse;
    }
}

extern "C" void kernel_launch(void* const* d_in, const int* in_sizes, int n_in,
                              void* d_out, int out_size, void* d_ws, size_t ws_size,
                              hipStream_t stream) {
    const float* x  = (const float*)d_in[0];
    const int*   ei = (const int*)d_in[1];
    const float* W1 = (const float*)d_in[2];
    const float* b1 = (const float*)d_in[3];
    const float* W2 = (const float*)d_in[4];
    const float* b2 = (const float*)d_in[5];
    float* out = (float*)d_out;

    const int N = NNODES;
    const int E = in_sizes[1] / 2;            // 8,000,000
    const int* src = ei;
    const int* dst = ei + E;
    const int NB = (N + BSIZE - 1) / BSIZE;   // 977

    int*          ws_i         = (int*)d_ws;
    int*          bucket_count = ws_i;                          // NB_PAD
    int*          base         = ws_i + NB_PAD;                 // NB_PAD + 1
    int*          cursor       = ws_i + 2 * NB_PAD + 1;         // NB_PAD
    unsigned int* packed       = (unsigned int*)(ws_i + 3 * NB_PAD + 1);  // E
    float*        dinv         = (float*)(packed + E);          // N
    float*        y1           = dinv + (size_t)N;              // 4N
    float*        y2           = y1 + (size_t)4 * N;            // 16N
    // total: 3073 + E + 21N words  ~= 74 MB

    hipMemsetAsync(bucket_count, 0, NB_PAD * sizeof(int), stream);

    const int B = 256;
    hist_kernel<<<GPLACE, B, 0, stream>>>(dst, bucket_count, E);
    scan_kernel<<<1, NB_PAD, 0, stream>>>(bucket_count, base, cursor);
    int C = (E + GPLACE - 1) / GPLACE;
    place_kernel<<<GPLACE, B, 0, stream>>>(src, dst, cursor, packed, E, C);
    degdinv_kernel<<<NB, B, 0, stream>>>(packed, base, dinv, N);
    y1_kernel<<<(N + B - 1) / B, B, 0, stream>>>(dinv, x, y1, N);
    agg1t1_kernel<<<NB, B, 0, stream>>>(packed, base, y1, dinv, W1, b1, y2, N);
    agg2t2_kernel<<<NB, B, 0, stream>>>(packed, base, y2, dinv, W2, b2, out, N);
}

// Round 4
// 1138.186 us; speedup vs baseline: 1.8427x; 1.0484x over previous
//
#include <hip/hip_runtime.h>
#include <hip/hip_bf16.h>
#include <hip/hip_fp16.h>

#define NNODES 500000
#define BSHIFT 8
#define BSIZE  256          // nodes per bucket == block size
#define NB_PAD 2048         // padded bucket count (NB = 1954)
#define GPLACE 512

// ---------- pass 1: global histogram of dst buckets ----------
__global__ __launch_bounds__(256) void hist_kernel(const int* __restrict__ dst,
                                                   int* __restrict__ bucket_count, int E) {
    __shared__ unsigned int h[NB_PAD];
    for (int i = threadIdx.x; i < NB_PAD; i += blockDim.x) h[i] = 0u;
    __syncthreads();
    int stride = gridDim.x * blockDim.x;
    for (int i = blockIdx.x * blockDim.x + threadIdx.x; i < E; i += stride)
        atomicAdd(&h[((unsigned)dst[i]) >> BSHIFT], 1u);
    __syncthreads();
    for (int b = threadIdx.x; b < NB_PAD; b += blockDim.x) {
        unsigned c = h[b];
        if (c) atomicAdd(&bucket_count[b], (int)c);
    }
}

// ---------- pass 2: exclusive scan over 2048 buckets (1024 threads, 2 each) ----------
__global__ __launch_bounds__(1024) void scan_kernel(const int* __restrict__ bc,
                                                    int* __restrict__ base,
                                                    int* __restrict__ cursor) {
    __shared__ int s[1024];
    int t = threadIdx.x;
    int a = bc[2 * t], b = bc[2 * t + 1];
    s[t] = a + b;
    __syncthreads();
    for (int off = 1; off < 1024; off <<= 1) {
        int v = (t >= off) ? s[t - off] : 0;
        __syncthreads();
        s[t] += v;
        __syncthreads();
    }
    int excl = s[t] - a - b;
    base[2 * t] = excl;     base[2 * t + 1] = excl + a;
    cursor[2 * t] = excl;   cursor[2 * t + 1] = excl + a;
    if (t == 1023) base[2048] = s[1023];
}

// ---------- pass 3: place edges, packed = (dst&255)<<19 | src ----------
__global__ __launch_bounds__(256) void place_kernel(const int* __restrict__ src,
                                                    const int* __restrict__ dst,
                                                    int* __restrict__ cursor,
                                                    unsigned int* __restrict__ packed,
                                                    int E, int C) {
    __shared__ unsigned int h[NB_PAD];
    __shared__ int cur[NB_PAD];
    for (int i = threadIdx.x; i < NB_PAD; i += blockDim.x) h[i] = 0u;
    __syncthreads();
    int lo = blockIdx.x * C;
    int hi = min(E, lo + C);
    for (int i = lo + threadIdx.x; i < hi; i += blockDim.x)
        atomicAdd(&h[((unsigned)dst[i]) >> BSHIFT], 1u);
    __syncthreads();
    for (int b = threadIdx.x; b < NB_PAD; b += blockDim.x) {
        unsigned c = h[b];
        cur[b] = c ? atomicAdd(&cursor[b], (int)c) : 0;
    }
    __syncthreads();
    for (int i = lo + threadIdx.x; i < hi; i += blockDim.x) {
        unsigned d = (unsigned)dst[i];
        unsigned b = d >> BSHIFT;
        int pos = atomicAdd(&cur[b], 1);
        packed[pos] = ((d & (unsigned)(BSIZE - 1)) << 19) | (unsigned)src[i];
    }
}

// ---------- pass 4: degree -> dinv ----------
__global__ __launch_bounds__(256) void degdinv_kernel(const unsigned int* __restrict__ packed,
                                                      const int* __restrict__ base,
                                                      float* __restrict__ dinv, int n) {
    __shared__ unsigned int cnt[BSIZE];
    int b = blockIdx.x;
    cnt[threadIdx.x] = 0u;
    __syncthreads();
    int beg = base[b], end = base[b + 1];
    for (int i = beg + threadIdx.x; i < end; i += blockDim.x)
        atomicAdd(&cnt[packed[i] >> 19], 1u);
    __syncthreads();
    int v = (b << BSHIFT) + threadIdx.x;
    if (v < n) dinv[v] = rsqrtf((float)cnt[threadIdx.x] + 1.0f);
}

// ---------- y1h = fp16(dinv * x), stride 4 halves ----------
__global__ __launch_bounds__(256) void y1_kernel(const float* __restrict__ dinv,
                                                 const float* __restrict__ x,
                                                 __half* __restrict__ y1h, int n) {
    int v = blockIdx.x * blockDim.x + threadIdx.x;
    if (v >= n) return;
    float di = dinv[v];
    union { uint2 u; __half2 h[2]; } st;
    st.h[0] = __floats2half2_rn(di * x[3 * v + 0], di * x[3 * v + 1]);
    st.h[1] = __floats2half2_rn(di * x[3 * v + 2], 0.0f);
    *(uint2*)(y1h + 4 * (size_t)v) = st.u;
}

// ---------- layer 1: 1 lane/edge, 8B gather, LDS fp32 acc (pad 5), fused transform ----------
__global__ __launch_bounds__(256) void agg1t1_kernel(const unsigned int* __restrict__ packed,
                                                     const int* __restrict__ base,
                                                     const __half* __restrict__ y1h,
                                                     const float* __restrict__ dinv,
                                                     const float* __restrict__ x,
                                                     const float* __restrict__ W1,
                                                     const float* __restrict__ b1,
                                                     __half* __restrict__ y2h, int n) {
    __shared__ float acc[BSIZE * 5];          // 5 KB, padded stride
    int b = blockIdx.x;
    for (int i = threadIdx.x; i < BSIZE * 5; i += blockDim.x) acc[i] = 0.0f;
    __syncthreads();
    int beg = base[b], end = base[b + 1];
    const int STR = 256;
    int i = beg + threadIdx.x;
    for (; i + 3 * STR < end; i += 4 * STR) {
        unsigned p[4]; uint2 w[4];
#pragma unroll
        for (int u = 0; u < 4; ++u) p[u] = packed[i + u * STR];
#pragma unroll
        for (int u = 0; u < 4; ++u) {
            unsigned s = p[u] & 0x7FFFFu;
            w[u] = *(const uint2*)(y1h + 4 * (size_t)s);
        }
#pragma unroll
        for (int u = 0; u < 4; ++u) {
            unsigned dl = p[u] >> 19;
            float* ap = acc + dl * 5;
            union { uint2 u2; __half2 h[2]; } g; g.u2 = w[u];
            float2 f01 = __half22float2(g.h[0]);
            float2 f23 = __half22float2(g.h[1]);
            atomicAdd(ap + 0, f01.x);
            atomicAdd(ap + 1, f01.y);
            atomicAdd(ap + 2, f23.x);
        }
    }
    for (; i < end; i += STR) {
        unsigned p = packed[i];
        unsigned s = p & 0x7FFFFu;
        unsigned dl = p >> 19;
        union { uint2 u2; __half2 h[2]; } g;
        g.u2 = *(const uint2*)(y1h + 4 * (size_t)s);
        float2 f01 = __half22float2(g.h[0]);
        float2 f23 = __half22float2(g.h[1]);
        float* ap = acc + dl * 5;
        atomicAdd(ap + 0, f01.x);
        atomicAdd(ap + 1, f01.y);
        atomicAdd(ap + 2, f23.x);
    }
    __syncthreads();
    int t = threadIdx.x;
    int v = (b << BSHIFT) + t;
    if (v >= n) return;
    float di = dinv[v];
    float a0 = di * (acc[t * 5 + 0] + di * x[3 * v + 0]);
    float a1 = di * (acc[t * 5 + 1] + di * x[3 * v + 1]);
    float a2 = di * (acc[t * 5 + 2] + di * x[3 * v + 2]);
    float hf[16];
#pragma unroll
    for (int j = 0; j < 16; ++j) {
        float h = b1[j] + a0 * W1[0 * 16 + j] + a1 * W1[1 * 16 + j] + a2 * W1[2 * 16 + j];
        hf[j] = di * fmaxf(h, 0.0f);
    }
    union { uint4 u[2]; __half2 h[8]; } st;
#pragma unroll
    for (int q = 0; q < 8; ++q) st.h[q] = __floats2half2_rn(hf[2 * q], hf[2 * q + 1]);
    uint4* dp = (uint4*)(y2h + 16 * (size_t)v);
    dp[0] = st.u[0];
    dp[1] = st.u[1];
}

// ---------- layer 2: 2 lanes/edge, 16B gathers, LDS fp32 acc (pad 17), fused transform ----------
__global__ __launch_bounds__(256) void agg2t2_kernel(const unsigned int* __restrict__ packed,
                                                     const int* __restrict__ base,
                                                     const __half* __restrict__ y2h,
                                                     const float* __restrict__ dinv,
                                                     const float* __restrict__ W2,
                                                     const float* __restrict__ b2,
                                                     float* __restrict__ out, int n) {
    __shared__ float acc[BSIZE * 17];         // 17.4 KB, padded stride
    int b = blockIdx.x;
    for (int i = threadIdx.x; i < BSIZE * 17; i += blockDim.x) acc[i] = 0.0f;
    __syncthreads();
    int beg = base[b], end = base[b + 1];
    int f2 = threadIdx.x & 1;                 // half-row selector
    int slot = threadIdx.x >> 1;              // 128 edge slots
    const int STR = 128;
    int i = beg + slot;
    for (; i + 3 * STR < end; i += 4 * STR) {
        unsigned p[4]; uint4 w[4];
#pragma unroll
        for (int u = 0; u < 4; ++u) p[u] = packed[i + u * STR];
#pragma unroll
        for (int u = 0; u < 4; ++u) {
            unsigned s = p[u] & 0x7FFFFu;
            w[u] = *(const uint4*)(y2h + 16 * (size_t)s + 8 * f2);
        }
#pragma unroll
        for (int u = 0; u < 4; ++u) {
            unsigned dl = p[u] >> 19;
            float* ap = acc + dl * 17 + 8 * f2;
            union { uint4 u4; __half2 h[4]; } g; g.u4 = w[u];
#pragma unroll
            for (int q = 0; q < 4; ++q) {
                float2 f = __half22float2(g.h[q]);
                atomicAdd(ap + 2 * q + 0, f.x);
                atomicAdd(ap + 2 * q + 1, f.y);
            }
        }
    }
    for (; i < end; i += STR) {
        unsigned p = packed[i];
        unsigned s = p & 0x7FFFFu;
        unsigned dl = p >> 19;
        union { uint4 u4; __half2 h[4]; } g;
        g.u4 = *(const uint4*)(y2h + 16 * (size_t)s + 8 * f2);
        float* ap = acc + dl * 17 + 8 * f2;
#pragma unroll
        for (int q = 0; q < 4; ++q) {
            float2 f = __half22float2(g.h[q]);
            atomicAdd(ap + 2 * q + 0, f.x);
            atomicAdd(ap + 2 * q + 1, f.y);
        }
    }
    __syncthreads();
    int t = threadIdx.x;
    int v = (b << BSHIFT) + t;
    if (v >= n) return;
    float di = dinv[v];
    union { uint4 u[2]; __half2 h[8]; } sf;
    const uint4* sp = (const uint4*)(y2h + 16 * (size_t)v);
    sf.u[0] = sp[0];
    sf.u[1] = sp[1];
    float a[16];
#pragma unroll
    for (int q = 0; q < 8; ++q) {
        float2 f = __half22float2(sf.h[q]);
        a[2 * q + 0] = di * (acc[t * 17 + 2 * q + 0] + f.x);
        a[2 * q + 1] = di * (acc[t * 17 + 2 * q + 1] + f.y);
    }
    float z[10];
#pragma unroll
    for (int j = 0; j < 10; ++j) {
        float s = b2[j];
#pragma unroll
        for (int k = 0; k < 16; ++k) s += a[k] * W2[k * 10 + j];
        z[j] = s;
    }
    float m = z[0];
#pragma unroll
    for (int j = 1; j < 10; ++j) m = fmaxf(m, z[j]);
    float sum = 0.0f;
#pragma unroll
    for (int j = 0; j < 10; ++j) sum += expf(z[j] - m);
    float lse = logf(sum);
    float* ov = out + 10 * (size_t)v;
#pragma unroll
    for (int j = 0; j < 10; ++j) ov[j] = z[j] - m - lse;
}

extern "C" void kernel_launch(void* const* d_in, const int* in_sizes, int n_in,
                              void* d_out, int out_size, void* d_ws, size_t ws_size,
                              hipStream_t stream) {
    const float* x  = (const float*)d_in[0];
    const int*   ei = (const int*)d_in[1];
    const float* W1 = (const float*)d_in[2];
    const float* b1 = (const float*)d_in[3];
    const float* W2 = (const float*)d_in[4];
    const float* b2 = (const float*)d_in[5];
    float* out = (float*)d_out;

    const int N = NNODES;
    const int E = in_sizes[1] / 2;            // 8,000,000
    const int* src = ei;
    const int* dst = ei + E;
    const int NB = (N + BSIZE - 1) / BSIZE;   // 1954

    int*          ws_i         = (int*)d_ws;
    int*          bucket_count = ws_i;                           // NB_PAD
    int*          base         = ws_i + NB_PAD;                  // NB_PAD + 1
    int*          cursor       = ws_i + 2 * NB_PAD + 1;          // NB_PAD
    unsigned int* packed       = (unsigned int*)(ws_i + 3 * NB_PAD + 1);   // E
    float*        dinv         = (float*)(packed + E);           // N
    __half*       y1h          = (__half*)(dinv + (size_t)N);    // 4N halves
    __half*       y2h          = y1h + (size_t)4 * N;            // 16N halves
    // total ~ 6145 + E + N + 10N words ~= 54 MB

    hipMemsetAsync(bucket_count, 0, NB_PAD * sizeof(int), stream);

    const int B = 256;
    hist_kernel<<<GPLACE, B, 0, stream>>>(dst, bucket_count, E);
    scan_kernel<<<1, 1024, 0, stream>>>(bucket_count, base, cursor);
    int C = (E + GPLACE - 1) / GPLACE;
    place_kernel<<<GPLACE, B, 0, stream>>>(src, dst, cursor, packed, E, C);
    degdinv_kernel<<<NB, B, 0, stream>>>(packed, base, dinv, N);
    y1_kernel<<<(N + B - 1) / B, B, 0, stream>>>(dinv, x, y1h, N);
    agg1t1_kernel<<<NB, B, 0, stream>>>(packed, base, y1h, dinv, x, W1, b1, y2h, N);
    agg2t2_kernel<<<NB, B, 0, stream>>>(packed, base, y2h, dinv, W2, b2, out, N);
}